// Round 11
// baseline (27568.262 us; speedup 1.0000x reference)
//
#include <hip/hip_runtime.h>
#include <hip/hip_fp16.h>

#define Hh 2048
#define VV 256
#define SS 2048
#define TT 2048
#define NB 64
#define NT 256

typedef _Float16 h4 __attribute__((ext_vector_type(4)));
typedef _Float16 h2 __attribute__((ext_vector_type(2)));
typedef unsigned int u32x4 __attribute__((ext_vector_type(4)));

#if defined(__has_builtin)
#if __has_builtin(__builtin_amdgcn_fdot2)
#define FDOT2(a, b, c) __builtin_amdgcn_fdot2((a), (b), (c), false)
#endif
#endif
#ifndef FDOT2
#define FDOT2(a, b, c) \
  fmaf((float)(a).x, (float)(b).x, fmaf((float)(a).y, (float)(b).y, (c)))
#endif

#define SH(v, a, b) __builtin_shufflevector((v), (v), (a), (b))

// ---------------------------------------------------------------------------
// Generic NT GEMM: C[M][N] = A[M,K] . B[N,K]^T (+ biasM[m]) (+ biasN[n])
// ---------------------------------------------------------------------------
__global__ __launch_bounds__(256) void gemm_nt(const float* __restrict__ A,
                                               const float* __restrict__ B,
                                               const float* __restrict__ biasM,
                                               const float* __restrict__ biasN,
                                               float* __restrict__ C,
                                               int M, int N, int K) {
  __shared__ __align__(16) float At[32][68];
  __shared__ __align__(16) float Bt[32][68];
  const int t = threadIdx.x;
  const int m0 = blockIdx.x << 6, n0 = blockIdx.y << 6;
  const int r0 = t >> 3, c4 = (t & 7) << 2;
  const int tm = (t >> 4) << 2, tn = (t & 15) << 2;
  float acc[4][4];
#pragma unroll
  for (int i = 0; i < 4; ++i)
#pragma unroll
    for (int j = 0; j < 4; ++j) acc[i][j] = 0.f;

  for (int k0 = 0; k0 < K; k0 += 32) {
    float4 a0 = *(const float4*)&A[(size_t)(m0 + r0) * K + k0 + c4];
    float4 a1 = *(const float4*)&A[(size_t)(m0 + r0 + 32) * K + k0 + c4];
    float4 b0 = *(const float4*)&B[(size_t)(n0 + r0) * K + k0 + c4];
    float4 b1 = *(const float4*)&B[(size_t)(n0 + r0 + 32) * K + k0 + c4];
    __syncthreads();
    At[c4 + 0][r0] = a0.x; At[c4 + 1][r0] = a0.y; At[c4 + 2][r0] = a0.z; At[c4 + 3][r0] = a0.w;
    At[c4 + 0][r0 + 32] = a1.x; At[c4 + 1][r0 + 32] = a1.y; At[c4 + 2][r0 + 32] = a1.z; At[c4 + 3][r0 + 32] = a1.w;
    Bt[c4 + 0][r0] = b0.x; Bt[c4 + 1][r0] = b0.y; Bt[c4 + 2][r0] = b0.z; Bt[c4 + 3][r0] = b0.w;
    Bt[c4 + 0][r0 + 32] = b1.x; Bt[c4 + 1][r0 + 32] = b1.y; Bt[c4 + 2][r0 + 32] = b1.z; Bt[c4 + 3][r0 + 32] = b1.w;
    __syncthreads();
#pragma unroll
    for (int k = 0; k < 32; ++k) {
      float4 av = *(const float4*)&At[k][tm];
      float4 bv = *(const float4*)&Bt[k][tn];
      acc[0][0] = fmaf(av.x, bv.x, acc[0][0]);
      acc[0][1] = fmaf(av.x, bv.y, acc[0][1]);
      acc[0][2] = fmaf(av.x, bv.z, acc[0][2]);
      acc[0][3] = fmaf(av.x, bv.w, acc[0][3]);
      acc[1][0] = fmaf(av.y, bv.x, acc[1][0]);
      acc[1][1] = fmaf(av.y, bv.y, acc[1][1]);
      acc[1][2] = fmaf(av.y, bv.z, acc[1][2]);
      acc[1][3] = fmaf(av.y, bv.w, acc[1][3]);
      acc[2][0] = fmaf(av.z, bv.x, acc[2][0]);
      acc[2][1] = fmaf(av.z, bv.y, acc[2][1]);
      acc[2][2] = fmaf(av.z, bv.z, acc[2][2]);
      acc[2][3] = fmaf(av.z, bv.w, acc[2][3]);
      acc[3][0] = fmaf(av.w, bv.x, acc[3][0]);
      acc[3][1] = fmaf(av.w, bv.y, acc[3][1]);
      acc[3][2] = fmaf(av.w, bv.z, acc[3][2]);
      acc[3][3] = fmaf(av.w, bv.w, acc[3][3]);
    }
  }
#pragma unroll
  for (int i = 0; i < 4; ++i) {
    float bm = biasM ? biasM[m0 + tm + i] : 0.f;
#pragma unroll
    for (int j = 0; j < 4; ++j) {
      float bn = biasN ? biasN[n0 + tn + j] : 0.f;
      C[(size_t)(m0 + tm + i) * N + n0 + tn + j] = acc[i][j] + bm + bn;
    }
  }
}

// ---------------------------------------------------------------------------
// Persistent recurrence kernel — R1/R7 tagged-dataflow, NB=64 x NT=256.
//
// hb: compact uint32[2][2048]; slot = (16-bit epoch tag << 16 | fp16 h bits).
// Reader of step s polls buffer s&1 for tag s+1 (two dwordx4 cover its 8
// slots). Producer at step s publishes tag s+2 into buffer (s+1)&1 via
// relaxed agent store. Init: owner block writes tag 1 to its 32 slots. Tags
// +1-offset; max tag 4097 < 2^16.
//
// Block-count lever, clean NB=64 test (ledger: 256->18.55ms, 128->14.9ms;
// R10 proved poller-count within a block is irrelevant AND that a 4-wave
// 256-thread block gets the 1-wave/SIMD ~512-VGPR budget, no spill at 232).
// 32 rows/block, 8 rows/wave: wreg[8][24] = 384 VGPRs of fp16 weights +
// ~50 working < 512. Barrier convoy stays 4 waves (R9's 16-wave trap
// avoided). Pollers 16K, publishers 64, straggler max over 64 blocks.
//
// Buffer-reuse safety: identical transitive chain to R1 — a producer writes
// epoch e+2 only after polling ALL of e+1, which requires every block to
// have fully read epoch e (each block's tag-(e+1) publish sits after its
// barrier-synchronized staging of epoch e).
// ---------------------------------------------------------------------------
__global__ __launch_bounds__(NT) void recur_kernel(
    const float* __restrict__ giT_enc, const float* __restrict__ giT_dec,
    const float* __restrict__ enc_w_hh, const float* __restrict__ enc_b_hh,
    const float* __restrict__ dec_w_hh, const float* __restrict__ dec_b_hh,
    const int* __restrict__ inputs, const int* __restrict__ targets,
    unsigned int* __restrict__ hb, float* __restrict__ dec_hs) {
  __shared__ __align__(16) float gi_lds[96 * VV];       // 96 KB
  __shared__ __align__(16) _Float16 h16[2][Hh];         // 8 KB (double buffer)
  __shared__ __align__(16) unsigned short tok_lds[SS];  // 4 KB
  __shared__ float gidec_lds[192];

  const int t = threadIdx.x;
  const int b = blockIdx.x;
  const int bks = b << 5;  // 32 rows per block
  const int w = t >> 6, l = t & 63;  // 4 waves
  const int ri = (w << 3) + (l & 7);  // this lane's epilogue row (in-block)

  // ---- recurrent weights + biases: EIGHT rows per wave, all in registers
  h4 wreg[8][24];  // [row][gate*8+q]; statically indexed via full unroll
  float br_, bz_, bn_;
  auto load_wb = [&](const float* W, const float* B) {
#pragma unroll
    for (int r = 0; r < 8; ++r) {
#pragma unroll
      for (int g = 0; g < 3; ++g) {
        const float* rb =
            W + ((size_t)(g * Hh + bks + (w << 3) + r)) * Hh + (l << 2);
#pragma unroll
        for (int q = 0; q < 8; ++q) {
          float4 vv = *(const float4*)&rb[q * 256];
          wreg[r][g * 8 + q] = h4{(_Float16)vv.x, (_Float16)vv.y,
                                  (_Float16)vv.z, (_Float16)vv.w};
        }
      }
    }
    br_ = B[bks + ri];
    bz_ = B[Hh + bks + ri];
    bn_ = B[2 * Hh + bks + ri];
  };
  load_wb(enc_w_hh, enc_b_hh);

  // ---- stage encoder per-vocab input-gate slice: gi_lds[(g*32+rr)*256 + v]
  for (int i = t; i < 96 * 64; i += NT) {
    const int r = i >> 6, c = i & 63;
    const int g = r >> 5, rr = r & 31;
    ((float4*)&gi_lds[r * VV])[c] =
        ((const float4*)(giT_enc + ((size_t)(g * Hh + bks + rr)) * VV))[c];
  }

  // ---- tokens
  for (int u = t; u < SS; u += NT) tok_lds[u] = (unsigned short)inputs[u];

  // ---- decoder input-gates: only tokens {0, targets[1]}
  if (t < 192) {
    const int sel = t / 96, r96 = t % 96;
    const int tk = sel ? targets[1] : 0;
    const int g = r96 >> 5, rr = r96 & 31;
    gidec_lds[sel * 96 + r96] = giT_dec[((size_t)(g * Hh + bks + rr)) * VV + tk];
  }

  // ---- init own h slots: fp16 0.0 (bits 0), tag 1 (buffer 0)
  if (t < 32) {
    __hip_atomic_store(&hb[bks + t], 0x00010000u, __ATOMIC_RELAXED,
                       __HIP_MEMORY_SCOPE_AGENT);
  }
  float hprev = 0.0f;  // lanes 0..7 of wave w: running fp32 h[bks+8w+l]

  for (int step = 0; step < SS + TT; ++step) {
    if (step == SS) load_wb(dec_w_hh, dec_b_hh);  // private regs: no hazard
    const int sb = step & 1;

    // ---- poll the 8 tagged 32-bit slots this thread stages (2x dwordx4)
    {
      const unsigned int* addr = hb + ((size_t)sb << 11) + (t << 3);
      const unsigned int want = ((unsigned int)(step + 1)) << 16;
      u32x4 va, vb;
      for (;;) {
        asm volatile(
            "global_load_dwordx4 %0, %2, off sc0 sc1\n\t"
            "global_load_dwordx4 %1, %2, off offset:16 sc0 sc1\n\t"
            "s_waitcnt vmcnt(0)"
            : "=&v"(va), "=&v"(vb)
            : "v"(addr)
            : "memory");
        unsigned int bad =
            (va.x ^ want) | (va.y ^ want) | (va.z ^ want) | (va.w ^ want);
        bad |= (vb.x ^ want) | (vb.y ^ want) | (vb.z ^ want) | (vb.w ^ want);
        if ((bad & 0xFFFF0000u) == 0u) break;
        __builtin_amdgcn_s_sleep(1);
      }
      u32x4 packed = {(va.x & 0xFFFFu) | (va.y << 16),
                      (va.z & 0xFFFFu) | (va.w << 16),
                      (vb.x & 0xFFFFu) | (vb.y << 16),
                      (vb.z & 0xFFFFu) | (vb.w << 16)};
      *(u32x4*)&h16[sb][t << 3] = packed;
    }
    __syncthreads();  // also covers one-time gi_lds/tok_lds staging at step 0

    // ---- 24 gate-row dot products (8 rows x 3 gates), fp16 dot2, fp32 acc
    float ar[8], az[8], an[8];
#pragma unroll
    for (int r = 0; r < 8; ++r) { ar[r] = 0.f; az[r] = 0.f; an[r] = 0.f; }
#pragma unroll
    for (int q = 0; q < 8; ++q) {
      const int c = q * 256 + (l << 2);
      h4 hv = *(const h4*)&h16[sb][c];
      h2 hlo = SH(hv, 0, 1);
      h2 hhi = SH(hv, 2, 3);
#pragma unroll
      for (int r = 0; r < 8; ++r) {
        h4 wr4 = wreg[r][q], wz4 = wreg[r][8 + q], wn4 = wreg[r][16 + q];
        ar[r] = FDOT2(SH(wr4, 0, 1), hlo, ar[r]);
        ar[r] = FDOT2(SH(wr4, 2, 3), hhi, ar[r]);
        az[r] = FDOT2(SH(wz4, 0, 1), hlo, az[r]);
        az[r] = FDOT2(SH(wz4, 2, 3), hhi, az[r]);
        an[r] = FDOT2(SH(wn4, 0, 1), hlo, an[r]);
        an[r] = FDOT2(SH(wn4, 2, 3), hhi, an[r]);
      }
    }

    // ---- gate inputs hoisted above the reduce (row-matched via ri)
    float gr, gz, gn;
    if (step < SS) {
      const int tk = tok_lds[step];
      gr = gi_lds[(0 + ri) * VV + tk];
      gz = gi_lds[(32 + ri) * VV + tk];
      gn = gi_lds[(64 + ri) * VV + tk];
    } else {
      const int sel = (step == SS) ? 0 : 96;
      gr = gidec_lds[sel + 0 + ri];
      gz = gidec_lds[sel + 32 + ri];
      gn = gidec_lds[sel + 64 + ri];
    }

#pragma unroll
    for (int off = 32; off > 0; off >>= 1) {
#pragma unroll
      for (int r = 0; r < 8; ++r) {
        ar[r] += __shfl_xor(ar[r], off);
        az[r] += __shfl_xor(az[r], off);
        an[r] += __shfl_xor(an[r], off);
      }
    }

    if (l < 8) {  // lane k -> row bks+8w+k  (static row select, rule #20)
      const float arS =
          (l & 4) ? ((l & 2) ? ((l & 1) ? ar[7] : ar[6]) : ((l & 1) ? ar[5] : ar[4]))
                  : ((l & 2) ? ((l & 1) ? ar[3] : ar[2]) : ((l & 1) ? ar[1] : ar[0]));
      const float azS =
          (l & 4) ? ((l & 2) ? ((l & 1) ? az[7] : az[6]) : ((l & 1) ? az[5] : az[4]))
                  : ((l & 2) ? ((l & 1) ? az[3] : az[2]) : ((l & 1) ? az[1] : az[0]));
      const float anS =
          (l & 4) ? ((l & 2) ? ((l & 1) ? an[7] : an[6]) : ((l & 1) ? an[5] : an[4]))
                  : ((l & 2) ? ((l & 1) ? an[3] : an[2]) : ((l & 1) ? an[1] : an[0]));
      const float xr = gr + arS + br_;
      const float xz = gz + azS + bz_;
      const float hn = anS + bn_;
      const float rr = 1.f / (1.f + __expf(-xr));
      const float zz = 1.f / (1.f + __expf(-xz));
      const float nn = tanhf(gn + rr * hn);
      const float hnew = (1.f - zz) * nn + zz * hprev;

      _Float16 hf = (_Float16)hnew;
      const unsigned int pk =
          (((unsigned int)(step + 2)) << 16) |
          (unsigned int)__builtin_bit_cast(unsigned short, hf);
      __hip_atomic_store(&hb[(((size_t)((step + 1) & 1)) << 11) + bks + ri], pk,
                         __ATOMIC_RELAXED, __HIP_MEMORY_SCOPE_AGENT);
      if (step >= SS) dec_hs[(size_t)(step - SS) * Hh + bks + ri] = hnew;
      hprev = hnew;
    }
    // no trailing barrier: h16 is double-buffered; weights/biases are private
  }
}

// ---------------------------------------------------------------------------
extern "C" void kernel_launch(void* const* d_in, const int* in_sizes, int n_in,
                              void* d_out, int out_size, void* d_ws, size_t ws_size,
                              hipStream_t stream) {
  (void)in_sizes; (void)n_in; (void)out_size; (void)ws_size;
  const int* inputs = (const int*)d_in[0];
  const int* targets = (const int*)d_in[1];
  const float* emb = (const float*)d_in[2];
  const float* enc_w_ih = (const float*)d_in[3];
  const float* enc_w_hh = (const float*)d_in[4];
  const float* enc_b_ih = (const float*)d_in[5];
  const float* enc_b_hh = (const float*)d_in[6];
  const float* dec_w_ih = (const float*)d_in[7];
  const float* dec_w_hh = (const float*)d_in[8];
  const float* dec_b_ih = (const float*)d_in[9];
  const float* dec_b_hh = (const float*)d_in[10];
  const float* fc_w = (const float*)d_in[11];
  const float* fc_b = (const float*)d_in[12];
  float* out = (float*)d_out;

  // workspace layout
  float* giT_enc = (float*)d_ws;                          // [6144][256]
  float* giT_dec = giT_enc + (size_t)6144 * 256;          // [6144][256]
  float* dec_hs = giT_dec + (size_t)6144 * 256;           // [2048][2048]
  unsigned int* hb =
      (unsigned int*)(dec_hs + (size_t)TT * Hh);          // [2][2048] tagged u32

  // per-vocab input-gate tables: giT[r][v] = W_ih[r] . emb[v] + b_ih[r]
  gemm_nt<<<dim3(96, 4), 256, 0, stream>>>(enc_w_ih, emb, enc_b_ih, nullptr,
                                           giT_enc, 3 * Hh, VV, Hh);
  gemm_nt<<<dim3(96, 4), 256, 0, stream>>>(dec_w_ih, emb, dec_b_ih, nullptr,
                                           giT_dec, 3 * Hh, VV, Hh);

  void* args[] = {&giT_enc, &giT_dec, &enc_w_hh, &enc_b_hh, &dec_w_hh,
                  &dec_b_hh, &inputs, &targets, &hb, &dec_hs};
  hipError_t e = hipLaunchCooperativeKernel((void*)recur_kernel, dim3(NB),
                                            dim3(NT), args, 0, stream);
  if (e != hipSuccess) {
    recur_kernel<<<dim3(NB), dim3(NT), 0, stream>>>(
        giT_enc, giT_dec, enc_w_hh, enc_b_hh, dec_w_hh, dec_b_hh, inputs,
        targets, hb, dec_hs);
  }

  // out[t][v] = dec_hs[t] . fc_w[v] + fc_b[v]
  gemm_nt<<<dim3(32, 4), 256, 0, stream>>>(dec_hs, fc_w, nullptr, fc_b, out,
                                           TT, VV, Hh);
}

// Round 12
// 14905.470 us; speedup vs baseline: 1.8495x; 1.8495x over previous
//
#include <hip/hip_runtime.h>
#include <hip/hip_fp16.h>

#define Hh 2048
#define VV 256
#define SS 2048
#define TT 2048
#define NB 128
#define NT 512

typedef _Float16 h4 __attribute__((ext_vector_type(4)));
typedef _Float16 h2 __attribute__((ext_vector_type(2)));
typedef unsigned int u32x4 __attribute__((ext_vector_type(4)));
typedef unsigned short u16x4 __attribute__((ext_vector_type(4)));

#if defined(__has_builtin)
#if __has_builtin(__builtin_amdgcn_fdot2)
#define FDOT2(a, b, c) __builtin_amdgcn_fdot2((a), (b), (c), false)
#endif
#endif
#ifndef FDOT2
#define FDOT2(a, b, c) \
  fmaf((float)(a).x, (float)(b).x, fmaf((float)(a).y, (float)(b).y, (c)))
#endif

#define SH(v, a, b) __builtin_shufflevector((v), (v), (a), (b))

// ---------------------------------------------------------------------------
// Generic NT GEMM: C[M][N] = A[M,K] . B[N,K]^T (+ biasM[m]) (+ biasN[n])
// ---------------------------------------------------------------------------
__global__ __launch_bounds__(256) void gemm_nt(const float* __restrict__ A,
                                               const float* __restrict__ B,
                                               const float* __restrict__ biasM,
                                               const float* __restrict__ biasN,
                                               float* __restrict__ C,
                                               int M, int N, int K) {
  __shared__ __align__(16) float At[32][68];
  __shared__ __align__(16) float Bt[32][68];
  const int t = threadIdx.x;
  const int m0 = blockIdx.x << 6, n0 = blockIdx.y << 6;
  const int r0 = t >> 3, c4 = (t & 7) << 2;
  const int tm = (t >> 4) << 2, tn = (t & 15) << 2;
  float acc[4][4];
#pragma unroll
  for (int i = 0; i < 4; ++i)
#pragma unroll
    for (int j = 0; j < 4; ++j) acc[i][j] = 0.f;

  for (int k0 = 0; k0 < K; k0 += 32) {
    float4 a0 = *(const float4*)&A[(size_t)(m0 + r0) * K + k0 + c4];
    float4 a1 = *(const float4*)&A[(size_t)(m0 + r0 + 32) * K + k0 + c4];
    float4 b0 = *(const float4*)&B[(size_t)(n0 + r0) * K + k0 + c4];
    float4 b1 = *(const float4*)&B[(size_t)(n0 + r0 + 32) * K + k0 + c4];
    __syncthreads();
    At[c4 + 0][r0] = a0.x; At[c4 + 1][r0] = a0.y; At[c4 + 2][r0] = a0.z; At[c4 + 3][r0] = a0.w;
    At[c4 + 0][r0 + 32] = a1.x; At[c4 + 1][r0 + 32] = a1.y; At[c4 + 2][r0 + 32] = a1.z; At[c4 + 3][r0 + 32] = a1.w;
    Bt[c4 + 0][r0] = b0.x; Bt[c4 + 1][r0] = b0.y; Bt[c4 + 2][r0] = b0.z; Bt[c4 + 3][r0] = b0.w;
    Bt[c4 + 0][r0 + 32] = b1.x; Bt[c4 + 1][r0 + 32] = b1.y; Bt[c4 + 2][r0 + 32] = b1.z; Bt[c4 + 3][r0 + 32] = b1.w;
    __syncthreads();
#pragma unroll
    for (int k = 0; k < 32; ++k) {
      float4 av = *(const float4*)&At[k][tm];
      float4 bv = *(const float4*)&Bt[k][tn];
      acc[0][0] = fmaf(av.x, bv.x, acc[0][0]);
      acc[0][1] = fmaf(av.x, bv.y, acc[0][1]);
      acc[0][2] = fmaf(av.x, bv.z, acc[0][2]);
      acc[0][3] = fmaf(av.x, bv.w, acc[0][3]);
      acc[1][0] = fmaf(av.y, bv.x, acc[1][0]);
      acc[1][1] = fmaf(av.y, bv.y, acc[1][1]);
      acc[1][2] = fmaf(av.y, bv.z, acc[1][2]);
      acc[1][3] = fmaf(av.y, bv.w, acc[1][3]);
      acc[2][0] = fmaf(av.z, bv.x, acc[2][0]);
      acc[2][1] = fmaf(av.z, bv.y, acc[2][1]);
      acc[2][2] = fmaf(av.z, bv.z, acc[2][2]);
      acc[2][3] = fmaf(av.z, bv.w, acc[2][3]);
      acc[3][0] = fmaf(av.w, bv.x, acc[3][0]);
      acc[3][1] = fmaf(av.w, bv.y, acc[3][1]);
      acc[3][2] = fmaf(av.w, bv.z, acc[3][2]);
      acc[3][3] = fmaf(av.w, bv.w, acc[3][3]);
    }
  }
#pragma unroll
  for (int i = 0; i < 4; ++i) {
    float bm = biasM ? biasM[m0 + tm + i] : 0.f;
#pragma unroll
    for (int j = 0; j < 4; ++j) {
      float bn = biasN ? biasN[n0 + tn + j] : 0.f;
      C[(size_t)(m0 + tm + i) * N + n0 + tn + j] = acc[i][j] + bm + bn;
    }
  }
}

// ---------------------------------------------------------------------------
// Persistent recurrence kernel — R1/R7 tagged-dataflow, NB=128 x NT=512.
// EXACT revert to the session-best R7 configuration (14.9 ms verified).
//
// hb: compact uint32[2][2048]; slot = (16-bit epoch tag << 16 | fp16 h bits).
// Reader of step s polls buffer s&1 for tag s+1 (one dwordx4 sc0 sc1 covers
// its 4 slots). Producer at step s publishes tag s+2 into buffer (s+1)&1 via
// relaxed agent store. Init: owner block writes tag 1 to its 16 slots. Tags
// +1-offset; max tag 4097 < 2^16.
//
// Configuration rationale (12-round ledger):
//  - NB=128 is the block-count optimum: 256 -> 18.55ms, 128 -> 14.9ms;
//    NB=64 is architecturally closed (weights need >256 addressable VGPRs
//    per lane -> spill [R11]; 8/16-wave blocks cap at 128/64 VGPR [R8/R9]).
//  - Poller count per block is irrelevant (R10 null); traffic volume,
//    line layout, publish mechanism, detect mechanism all exonerated or
//    regress (R1-R6).
//  - 2 rows/wave, 2 register weight sets = 96 fp16 VGPRs, ~124 total.
//
// Buffer-reuse safety: a producer writes epoch e+2 only after polling ALL of
// e+1, which requires every block to have fully read epoch e (each block's
// tag-(e+1) publish sits after its barrier-synchronized staging of epoch e).
// ---------------------------------------------------------------------------
__global__ __launch_bounds__(NT) void recur_kernel(
    const float* __restrict__ giT_enc, const float* __restrict__ giT_dec,
    const float* __restrict__ enc_w_hh, const float* __restrict__ enc_b_hh,
    const float* __restrict__ dec_w_hh, const float* __restrict__ dec_b_hh,
    const int* __restrict__ inputs, const int* __restrict__ targets,
    unsigned int* __restrict__ hb, float* __restrict__ dec_hs) {
  __shared__ __align__(16) float gi_lds[48 * VV];       // 48 KB
  __shared__ __align__(16) _Float16 h16[2][Hh];         // 8 KB (double buffer)
  __shared__ __align__(16) unsigned short tok_lds[SS];  // 4 KB
  __shared__ float gidec_lds[96];

  const int t = threadIdx.x;
  const int b = blockIdx.x;
  const int bks = b << 4;  // 16 rows per block
  const int w = t >> 6, l = t & 63;
  const int ri = (w << 1) + (l & 1);  // this lane's epilogue row (in-block)

  // ---- recurrent weights + biases: two rows per wave, all in registers
  h4 wregA[24], wregB[24];
  float br_, bz_, bn_;
  auto load_wb = [&](const float* W, const float* B) {
#pragma unroll
    for (int g = 0; g < 3; ++g) {
      const float* r0 = W + ((size_t)(g * Hh + bks + (w << 1) + 0)) * Hh + (l << 2);
      const float* r1 = W + ((size_t)(g * Hh + bks + (w << 1) + 1)) * Hh + (l << 2);
#pragma unroll
      for (int q = 0; q < 8; ++q) {
        float4 v0 = *(const float4*)&r0[q * 256];
        float4 v1 = *(const float4*)&r1[q * 256];
        wregA[g * 8 + q] = h4{(_Float16)v0.x, (_Float16)v0.y,
                             (_Float16)v0.z, (_Float16)v0.w};
        wregB[g * 8 + q] = h4{(_Float16)v1.x, (_Float16)v1.y,
                             (_Float16)v1.z, (_Float16)v1.w};
      }
    }
    br_ = B[bks + ri];
    bz_ = B[Hh + bks + ri];
    bn_ = B[2 * Hh + bks + ri];
  };
  load_wb(enc_w_hh, enc_b_hh);

  // ---- stage encoder per-vocab input-gate slice: gi_lds[(g*16+rr)*256 + v]
  for (int r = 0; r < 48; ++r) {
    const int g = r >> 4, rr = r & 15;
    const float4* src = (const float4*)(giT_enc + ((size_t)(g * Hh + bks + rr)) * VV);
    if (t < 64) ((float4*)&gi_lds[r * VV])[t] = src[t];
  }

  // ---- tokens
  for (int u = t; u < SS; u += NT) tok_lds[u] = (unsigned short)inputs[u];

  // ---- decoder input-gates: only tokens {0, targets[1]}
  if (t < 96) {
    const int sel = t / 48, r48 = t % 48;
    const int tk = sel ? targets[1] : 0;
    const int g = r48 >> 4, rr = r48 & 15;
    gidec_lds[sel * 48 + r48] = giT_dec[((size_t)(g * Hh + bks + rr)) * VV + tk];
  }

  // ---- init own h slots: fp16 0.0 (bits 0), tag 1 (buffer 0)
  if (t < 16) {
    __hip_atomic_store(&hb[bks + t], 0x00010000u, __ATOMIC_RELAXED,
                       __HIP_MEMORY_SCOPE_AGENT);
  }
  float hprev = 0.0f;  // lanes 0/1 of wave w: running fp32 h[bks+2w+l]

  for (int step = 0; step < SS + TT; ++step) {
    if (step == SS) load_wb(dec_w_hh, dec_b_hh);  // private regs: no hazard
    const int sb = step & 1;

    // ---- poll the 4 tagged 32-bit slots this thread stages (one dwordx4)
    {
      const unsigned int* addr = hb + ((size_t)sb << 11) + (t << 2);
      const unsigned int want = ((unsigned int)(step + 1)) << 16;
      u32x4 v;
      for (;;) {
        asm volatile(
            "global_load_dwordx4 %0, %1, off sc0 sc1\n\t"
            "s_waitcnt vmcnt(0)"
            : "=&v"(v)
            : "v"(addr)
            : "memory");
        if ((v.x & 0xFFFF0000u) == want && (v.y & 0xFFFF0000u) == want &&
            (v.z & 0xFFFF0000u) == want && (v.w & 0xFFFF0000u) == want)
          break;
        __builtin_amdgcn_s_sleep(1);
      }
      u16x4 hu = {(unsigned short)v.x, (unsigned short)v.y,
                  (unsigned short)v.z, (unsigned short)v.w};
      *(u16x4*)&h16[sb][t << 2] = hu;
    }
    __syncthreads();

    // ---- six gate-row dot products (2 rows x 3 gates), fp16 dot2, fp32 acc
    float arA = 0.f, azA = 0.f, anA = 0.f;
    float arB = 0.f, azB = 0.f, anB = 0.f;
#pragma unroll
    for (int q = 0; q < 8; ++q) {
      const int c = q * 256 + (l << 2);
      h4 hv = *(const h4*)&h16[sb][c];
      h2 hlo = SH(hv, 0, 1);
      h2 hhi = SH(hv, 2, 3);
      h4 a_r = wregA[q], a_z = wregA[8 + q], a_n = wregA[16 + q];
      h4 b_r = wregB[q], b_z = wregB[8 + q], b_n = wregB[16 + q];
      arA = FDOT2(SH(a_r, 0, 1), hlo, arA); arA = FDOT2(SH(a_r, 2, 3), hhi, arA);
      azA = FDOT2(SH(a_z, 0, 1), hlo, azA); azA = FDOT2(SH(a_z, 2, 3), hhi, azA);
      anA = FDOT2(SH(a_n, 0, 1), hlo, anA); anA = FDOT2(SH(a_n, 2, 3), hhi, anA);
      arB = FDOT2(SH(b_r, 0, 1), hlo, arB); arB = FDOT2(SH(b_r, 2, 3), hhi, arB);
      azB = FDOT2(SH(b_z, 0, 1), hlo, azB); azB = FDOT2(SH(b_z, 2, 3), hhi, azB);
      anB = FDOT2(SH(b_n, 0, 1), hlo, anB); anB = FDOT2(SH(b_n, 2, 3), hhi, anB);
    }

    // ---- gate inputs hoisted above the reduce (row-matched via ri)
    float gr, gz, gn;
    if (step < SS) {
      const int tk = tok_lds[step];
      gr = gi_lds[(0 + ri) * VV + tk];
      gz = gi_lds[(16 + ri) * VV + tk];
      gn = gi_lds[(32 + ri) * VV + tk];
    } else {
      const int sel = (step == SS) ? 0 : 48;
      gr = gidec_lds[sel + 0 + ri];
      gz = gidec_lds[sel + 16 + ri];
      gn = gidec_lds[sel + 32 + ri];
    }

#pragma unroll
    for (int off = 32; off > 0; off >>= 1) {
      arA += __shfl_xor(arA, off); azA += __shfl_xor(azA, off); anA += __shfl_xor(anA, off);
      arB += __shfl_xor(arB, off); azB += __shfl_xor(azB, off); anB += __shfl_xor(anB, off);
    }

    if (l < 2) {  // lane 0 -> row bks+2w, lane 1 -> row bks+2w+1
      const float ar = l ? arB : arA;
      const float az = l ? azB : azA;
      const float an = l ? anB : anA;
      const float xr = gr + ar + br_;
      const float xz = gz + az + bz_;
      const float hn = an + bn_;
      const float rr = 1.f / (1.f + __expf(-xr));
      const float zz = 1.f / (1.f + __expf(-xz));
      const float nn = tanhf(gn + rr * hn);
      const float hnew = (1.f - zz) * nn + zz * hprev;

      _Float16 hf = (_Float16)hnew;
      const unsigned int pk =
          (((unsigned int)(step + 2)) << 16) |
          (unsigned int)__builtin_bit_cast(unsigned short, hf);
      __hip_atomic_store(&hb[(((size_t)((step + 1) & 1)) << 11) + bks + ri], pk,
                         __ATOMIC_RELAXED, __HIP_MEMORY_SCOPE_AGENT);
      if (step >= SS) dec_hs[(size_t)(step - SS) * Hh + bks + ri] = hnew;
      hprev = hnew;
    }
    // no trailing barrier: h16 is double-buffered; weights/biases are private
  }
}

// ---------------------------------------------------------------------------
extern "C" void kernel_launch(void* const* d_in, const int* in_sizes, int n_in,
                              void* d_out, int out_size, void* d_ws, size_t ws_size,
                              hipStream_t stream) {
  (void)in_sizes; (void)n_in; (void)out_size; (void)ws_size;
  const int* inputs = (const int*)d_in[0];
  const int* targets = (const int*)d_in[1];
  const float* emb = (const float*)d_in[2];
  const float* enc_w_ih = (const float*)d_in[3];
  const float* enc_w_hh = (const float*)d_in[4];
  const float* enc_b_ih = (const float*)d_in[5];
  const float* enc_b_hh = (const float*)d_in[6];
  const float* dec_w_ih = (const float*)d_in[7];
  const float* dec_w_hh = (const float*)d_in[8];
  const float* dec_b_ih = (const float*)d_in[9];
  const float* dec_b_hh = (const float*)d_in[10];
  const float* fc_w = (const float*)d_in[11];
  const float* fc_b = (const float*)d_in[12];
  float* out = (float*)d_out;

  // workspace layout
  float* giT_enc = (float*)d_ws;                          // [6144][256]
  float* giT_dec = giT_enc + (size_t)6144 * 256;          // [6144][256]
  float* dec_hs = giT_dec + (size_t)6144 * 256;           // [2048][2048]
  unsigned int* hb =
      (unsigned int*)(dec_hs + (size_t)TT * Hh);          // [2][2048] tagged u32

  // per-vocab input-gate tables: giT[r][v] = W_ih[r] . emb[v] + b_ih[r]
  gemm_nt<<<dim3(96, 4), 256, 0, stream>>>(enc_w_ih, emb, enc_b_ih, nullptr,
                                           giT_enc, 3 * Hh, VV, Hh);
  gemm_nt<<<dim3(96, 4), 256, 0, stream>>>(dec_w_ih, emb, dec_b_ih, nullptr,
                                           giT_dec, 3 * Hh, VV, Hh);

  void* args[] = {&giT_enc, &giT_dec, &enc_w_hh, &enc_b_hh, &dec_w_hh,
                  &dec_b_hh, &inputs, &targets, &hb, &dec_hs};
  hipError_t e = hipLaunchCooperativeKernel((void*)recur_kernel, dim3(NB),
                                            dim3(NT), args, 0, stream);
  if (e != hipSuccess) {
    recur_kernel<<<dim3(NB), dim3(NT), 0, stream>>>(
        giT_enc, giT_dec, enc_w_hh, enc_b_hh, dec_w_hh, dec_b_hh, inputs,
        targets, hb, dec_hs);
  }

  // out[t][v] = dec_hs[t] . fc_w[v] + fc_b[v]
  gemm_nt<<<dim3(32, 4), 256, 0, stream>>>(dec_hs, fc_w, nullptr, fc_b, out,
                                           TT, VV, Hh);
}